// Round 6
// baseline (524.876 us; speedup 1.0000x reference)
//
#include <hip/hip_runtime.h>
#include <hip/hip_bf16.h>

typedef __bf16 bf16x8 __attribute__((ext_vector_type(8)));
typedef float f32x4 __attribute__((ext_vector_type(4)));
typedef unsigned short u16;

#define HEADS 12
#define DK 64
#define DM 768
#define SEQL 4096
#define BSZ 2
#define MROWS (BSZ * SEQL) /* 8192 */

// 1/sqrt(64) * log2(e): folded into the Q projection so flash softmax runs base-2.
#define QSCALE 0.180336880434245f

// bare v_exp_f32 (2^x) — __exp2f doesn't exist on this toolchain (R5 compile fail)
#define EXP2F(x) __builtin_amdgcn_exp2f(x)

__device__ __forceinline__ float bf2f(u16 x) {
    unsigned int u = ((unsigned int)x) << 16;
    return __uint_as_float(u);
}
__device__ __forceinline__ u16 f2bf(float f) {
    unsigned int u = __float_as_uint(f);
    u += 0x7fff + ((u >> 16) & 1);   // round-to-nearest-even
    return (u16)(u >> 16);
}

// Detect whether the float tensors are really f32 (reference dtype) or bf16.
__global__ void detect_dtype(const u16* __restrict__ q, int* __restrict__ flag) {
    __shared__ int cnt;
    if (threadIdx.x == 0) cnt = 0;
    __syncthreads();
    int c = 0;
    for (int i = threadIdx.x; i < 16384; i += 256) {
        u16 x = q[i];
        if (((x >> 7) & 0xFF) == 0xFF) c++;
    }
    if (c) atomicAdd(&cnt, c);
    __syncthreads();
    if (threadIdx.x == 0) *flag = (cnt > 0) ? 1 : 0;
}

// Stage 16 contiguous elements into LDS as bf16, from either dtype.
__device__ __forceinline__ void stage16_bf16(u16* dst, const u16* src) {
    *(uint4*)dst = *(const uint4*)src;
    *(uint4*)(dst + 8) = *(const uint4*)(src + 8);
}
__device__ __forceinline__ void stage16_f32(u16* dst, const float* src) {
#pragma unroll
    for (int g = 0; g < 2; ++g) {
        float4 f0 = ((const float4*)src)[2 * g];
        float4 f1 = ((const float4*)src)[2 * g + 1];
        ushort4 a = {f2bf(f0.x), f2bf(f0.y), f2bf(f0.z), f2bf(f0.w)};
        ushort4 b = {f2bf(f1.x), f2bf(f1.y), f2bf(f1.z), f2bf(f1.w)};
        *(ushort4*)(dst + 8 * g) = a;
        *(ushort4*)(dst + 8 * g + 4) = b;
    }
}

// Y = X (8192x768) @ W^T (768x768) + b, fp32 accum, out scaled by oscale.
// 128x128 block tile, BK=32, 4 waves each owning 64x64 (4x4 MFMA tiles).
template <int MODE, bool XFLAG>
__global__ __launch_bounds__(256) void gemm_proj(const void* __restrict__ Xv,
                                                 const void* __restrict__ Wv,
                                                 const void* __restrict__ biasv,
                                                 void* __restrict__ Yv,
                                                 const int* __restrict__ flag,
                                                 float oscale) {
    __shared__ __align__(16) u16 As[128][40];   // 128 x BK32 (+8 pad)
    __shared__ __align__(16) u16 Bs[128][40];

    const int f32mode = *flag;
    const bool xf = XFLAG && f32mode;
    const bool wf = f32mode != 0;

    const int tid  = threadIdx.x;
    const int lane = tid & 63;
    const int wave = tid >> 6;
    const int wrow = (wave >> 1) * 64;
    const int wcol = (wave & 1) * 64;
    const int l15  = lane & 15;
    const int quad = lane >> 4;
    const int m0   = blockIdx.x * 128;
    const int n0   = blockIdx.y * 128;

    const int srow = tid >> 1;
    const int scol = (tid & 1) * 16;

    f32x4 acc[4][4] = {};
    const size_t xoff = (size_t)(m0 + srow) * DM + scol;
    const size_t woff = (size_t)(n0 + srow) * DM + scol;

    for (int kb = 0; kb < DM; kb += 32) {
        if (xf) stage16_f32(&As[srow][scol], (const float*)Xv + xoff + kb);
        else    stage16_bf16(&As[srow][scol], (const u16*)Xv + xoff + kb);
        if (wf) stage16_f32(&Bs[srow][scol], (const float*)Wv + woff + kb);
        else    stage16_bf16(&Bs[srow][scol], (const u16*)Wv + woff + kb);
        __syncthreads();

        bf16x8 a[4], b[4];
#pragma unroll
        for (int i = 0; i < 4; ++i)
            a[i] = *(const bf16x8*)&As[wrow + i * 16 + l15][quad * 8];
#pragma unroll
        for (int j = 0; j < 4; ++j)
            b[j] = *(const bf16x8*)&Bs[wcol + j * 16 + l15][quad * 8];
#pragma unroll
        for (int i = 0; i < 4; ++i)
#pragma unroll
            for (int j = 0; j < 4; ++j)
                acc[i][j] = __builtin_amdgcn_mfma_f32_16x16x32_bf16(a[i], b[j], acc[i][j], 0, 0, 0);
        __syncthreads();
    }

#pragma unroll
    for (int j = 0; j < 4; ++j) {
        int o = n0 + wcol + j * 16 + l15;
        float bv = wf ? ((const float*)biasv)[o] : bf2f(((const u16*)biasv)[o]);
#pragma unroll
        for (int i = 0; i < 4; ++i) {
#pragma unroll
            for (int r = 0; r < 4; ++r) {
                int row = m0 + wrow + i * 16 + quad * 4 + r;
                float val = (acc[i][j][r] + bv) * oscale;
                if (MODE == 0) {
                    if (f32mode) ((float*)Yv)[(size_t)row * DM + o] = val;
                    else         ((u16*)Yv)[(size_t)row * DM + o] = f2bf(val);
                } else {
                    int bb = row >> 12, s = row & (SEQL - 1);
                    int h = o >> 6, d = o & 63;
                    if (MODE == 1)
                        ((u16*)Yv)[((bb * HEADS + h) << 18) + (s << 6) + d] = f2bf(val);
                    else
                        ((u16*)Yv)[((bb * HEADS + h) << 18) + (d << 12) + s] = f2bf(val);
                }
            }
        }
    }
}

// ---- flash v3: base-2 softmax, conditional rescale ----
typedef __attribute__((address_space(1))) unsigned int glb_u32;
typedef __attribute__((address_space(3))) unsigned int lds_u32;

__device__ __forceinline__ void gld16(const u16* g, u16* l) {
    __builtin_amdgcn_global_load_lds((glb_u32*)g, (lds_u32*)l, 16, 0, 0);
}

// Stage a 64x64 bf16 tile into 8KB LDS via global_load_lds; XOR chunk swizzle.
__device__ __forceinline__ void stage_tile(const u16* gbase, int rstride,
                                           u16* lbase, int tid) {
#pragma unroll
    for (int it = 0; it < 2; ++it) {
        int c = it * 256 + tid;
        int row = c >> 3, p = c & 7;
        int gc = p ^ (row & 7);
        gld16(gbase + (size_t)row * rstride + gc * 8, lbase + c * 8);
    }
}

// Q (pre-scaled by QSCALE),K: [b][h][s][d]; Vt: [b][h][d][s]; ctx: [b][s][h*64+d]
__global__ __launch_bounds__(256) void flash_attn(const u16* __restrict__ Q,
                                                  const u16* __restrict__ K,
                                                  const u16* __restrict__ Vt,
                                                  const int* __restrict__ mask,
                                                  u16* __restrict__ ctx) {
    __shared__ __align__(16) u16 Ks[2][64 * 64];
    __shared__ __align__(16) u16 Vs[2][64 * 64];
    __shared__ __align__(16) float Ms[2][64];
    __shared__ __align__(16) u16 Ps[4][16 * 72];

    const int tid  = threadIdx.x;
    const int lane = tid & 63;
    const int wave = tid >> 6;
    const int l15  = lane & 15;
    const int quad = lane >> 4;

    const int bh = blockIdx.y;
    const int b  = bh / HEADS;
    const int h  = bh - b * HEADS;
    const int qb = blockIdx.x * 64 + wave * 16;

    const u16* Qh = Q  + ((size_t)bh << 18);
    const u16* Kh = K  + ((size_t)bh << 18);
    const u16* Vh = Vt + ((size_t)bh << 18);
    const int* maskb = mask + b * SEQL;

    bf16x8 aq0 = *(const bf16x8*)&Qh[(size_t)(qb + l15) * DK + quad * 8];
    bf16x8 aq1 = *(const bf16x8*)&Qh[(size_t)(qb + l15) * DK + 32 + quad * 8];

    const int r7   = l15 & 7;
    const int ck0  = (quad ^ r7) * 8;
    const int ck1  = ((quad + 4) ^ r7) * 8;
    const int lrow = l15 * 64;

    float m_s = -3.0e38f, l_s = 0.f;
    f32x4 o_acc[4] = {};

    int mreg = 0;
    if (tid < 64) mreg = maskb[tid];
    stage_tile(Kh, DK, &Ks[0][0], tid);
    stage_tile(Vh, SEQL, &Vs[0][0], tid);
    if (tid < 64) {
        Ms[0][tid] = (mreg == 0) ? -1.0e9f : 0.0f;
        mreg = maskb[64 + tid];
    }
    __syncthreads();

    for (int t = 0; t < 64; ++t) {
        const int cur = t & 1, nxt = cur ^ 1;
        if (t < 63) {
            const int kt = (t + 1) * 64;
            stage_tile(Kh + (size_t)kt * DK, DK, &Ks[nxt][0], tid);
            stage_tile(Vh + kt, SEQL, &Vs[nxt][0], tid);
            if (tid < 64) {
                Ms[nxt][tid] = (mreg == 0) ? -1.0e9f : 0.0f;
                if (t < 62) mreg = maskb[(t + 2) * 64 + tid];
            }
        }

        const u16* kb = &Ks[cur][0];
        const u16* vb = &Vs[cur][0];

        // S^T (base-2 units): lane owns q=l15, kpos = nt*16 + quad*4 + r
        f32x4 s4[4];
#pragma unroll
        for (int nt = 0; nt < 4; ++nt) {
            bf16x8 ak0 = *(const bf16x8*)&kb[lrow + nt * 1024 + ck0];
            bf16x8 ak1 = *(const bf16x8*)&kb[lrow + nt * 1024 + ck1];
            f32x4 z = {};
            z = __builtin_amdgcn_mfma_f32_16x16x32_bf16(ak0, aq0, z, 0, 0, 0);
            z = __builtin_amdgcn_mfma_f32_16x16x32_bf16(ak1, aq1, z, 0, 0, 0);
            f32x4 bias = *(const f32x4*)&Ms[cur][nt * 16 + quad * 4];
#pragma unroll
            for (int r = 0; r < 4; ++r) s4[nt][r] = z[r] + bias[r];
        }

        float mx = -3.0e38f;
#pragma unroll
        for (int nt = 0; nt < 4; ++nt)
#pragma unroll
            for (int r = 0; r < 4; ++r) mx = fmaxf(mx, s4[nt][r]);
        mx = fmaxf(mx, __shfl_xor(mx, 16, 64));
        mx = fmaxf(mx, __shfl_xor(mx, 32, 64));
        float newm = fmaxf(m_s, mx);

        float rs = 0.f;
#pragma unroll
        for (int nt = 0; nt < 4; ++nt)
#pragma unroll
            for (int r = 0; r < 4; ++r) {
                float p = EXP2F(s4[nt][r] - newm);   // bare v_exp_f32
                s4[nt][r] = p;
                rs += p;
            }
        rs += __shfl_xor(rs, 16, 64);
        rs += __shfl_xor(rs, 32, 64);

        if (!__all(newm == m_s)) {                   // rare after warm-up
            float alpha = EXP2F(m_s - newm);
            l_s *= alpha;
#pragma unroll
            for (int dv = 0; dv < 4; ++dv)
#pragma unroll
                for (int r = 0; r < 4; ++r) o_acc[dv][r] *= alpha;
            m_s = newm;
        }
        l_s += rs;

#pragma unroll
        for (int nt = 0; nt < 4; ++nt) {
            union { __hip_bfloat162 h2[2]; uint2 u; } cv;
            cv.h2[0] = __float22bfloat162_rn(make_float2(s4[nt][0], s4[nt][1]));
            cv.h2[1] = __float22bfloat162_rn(make_float2(s4[nt][2], s4[nt][3]));
            *(uint2*)&Ps[wave][l15 * 72 + nt * 16 + quad * 4] = cv.u;
        }
        asm volatile("" ::: "memory");

        bf16x8 bp0 = *(const bf16x8*)&Ps[wave][l15 * 72 + quad * 8];
        bf16x8 bp1 = *(const bf16x8*)&Ps[wave][l15 * 72 + 32 + quad * 8];
#pragma unroll
        for (int dv = 0; dv < 4; ++dv) {
            bf16x8 av0 = *(const bf16x8*)&vb[lrow + dv * 1024 + ck0];
            bf16x8 av1 = *(const bf16x8*)&vb[lrow + dv * 1024 + ck1];
            o_acc[dv] = __builtin_amdgcn_mfma_f32_16x16x32_bf16(av0, bp0, o_acc[dv], 0, 0, 0);
            o_acc[dv] = __builtin_amdgcn_mfma_f32_16x16x32_bf16(av1, bp1, o_acc[dv], 0, 0, 0);
        }
        __syncthreads();
    }

    float inv = 1.0f / l_s;
#pragma unroll
    for (int dv = 0; dv < 4; ++dv) {
        union { __hip_bfloat162 h2[2]; uint2 u; } cv;
        cv.h2[0] = __float22bfloat162_rn(make_float2(o_acc[dv][0] * inv, o_acc[dv][1] * inv));
        cv.h2[1] = __float22bfloat162_rn(make_float2(o_acc[dv][2] * inv, o_acc[dv][3] * inv));
        *(uint2*)&Ps[wave][l15 * 72 + dv * 16 + quad * 4] = cv.u;
    }
    asm volatile("" ::: "memory");
    {
        int rowq = lane >> 2, dchunk = lane & 3;
        uint4 w0 = *(const uint4*)&Ps[wave][rowq * 72 + dchunk * 16];
        uint4 w1 = *(const uint4*)&Ps[wave][rowq * 72 + dchunk * 16 + 8];
        size_t orow = (size_t)(b * SEQL + qb + rowq) * DM + h * DK + dchunk * 16;
        *(uint4*)&ctx[orow] = w0;
        *(uint4*)&ctx[orow + 8] = w1;
    }
}

extern "C" void kernel_launch(void* const* d_in, const int* in_sizes, int n_in,
                              void* d_out, int out_size, void* d_ws, size_t ws_size,
                              hipStream_t stream) {
    const void* q   = d_in[0];
    const void* k   = d_in[1];
    const void* v   = d_in[2];
    const void* Wq  = d_in[3];
    const void* bq  = d_in[4];
    const void* Wk  = d_in[5];
    const void* bk  = d_in[6];
    const void* Wv  = d_in[7];
    const void* bv  = d_in[8];
    const void* Wo  = d_in[9];
    const void* bo  = d_in[10];
    const int* mask = (const int*)d_in[11];

    const size_t NSH = (size_t)BSZ * HEADS * SEQL * DK;
    const size_t need = 4 * NSH * sizeof(u16) + 256;
    if (ws_size < need) return;

    u16* ws  = (u16*)d_ws;
    u16* Qh  = ws;
    u16* Kh  = ws + NSH;
    u16* Vth = ws + 2 * NSH;
    u16* ctx = ws + 3 * NSH;
    int* dflag = (int*)((char*)d_ws + 4 * NSH * sizeof(u16));

    detect_dtype<<<1, 256, 0, stream>>>((const u16*)q, dflag);

    dim3 gg(MROWS / 128, DM / 128);
    gemm_proj<1, true><<<gg, 256, 0, stream>>>(q, Wq, bq, Qh, dflag, QSCALE);
    gemm_proj<1, true><<<gg, 256, 0, stream>>>(k, Wk, bk, Kh, dflag, 1.0f);
    gemm_proj<2, true><<<gg, 256, 0, stream>>>(v, Wv, bv, Vth, dflag, 1.0f);
    flash_attn<<<dim3(SEQL / 64, BSZ * HEADS), 256, 0, stream>>>(Qh, Kh, Vth, mask, ctx);
    gemm_proj<0, false><<<gg, 256, 0, stream>>>(ctx, Wo, bo, d_out, dflag, 1.0f);
}

// Round 7
// 444.867 us; speedup vs baseline: 1.1798x; 1.1798x over previous
//
#include <hip/hip_runtime.h>
#include <hip/hip_bf16.h>

typedef __bf16 bf16x8 __attribute__((ext_vector_type(8)));
typedef float f32x4 __attribute__((ext_vector_type(4)));
typedef unsigned short u16;

#define HEADS 12
#define DK 64
#define DM 768
#define SEQL 4096
#define BSZ 2
#define MROWS (BSZ * SEQL) /* 8192 */

// 1/sqrt(64) * log2(e): folded into Q projection so flash softmax runs base-2.
#define QSCALE 0.180336880434245f
#define EXP2F(x) __builtin_amdgcn_exp2f(x)

__device__ __forceinline__ float bf2f(u16 x) {
    unsigned int u = ((unsigned int)x) << 16;
    return __uint_as_float(u);
}
__device__ __forceinline__ u16 f2bf(float f) {
    unsigned int u = __float_as_uint(f);
    u += 0x7fff + ((u >> 16) & 1);
    return (u16)(u >> 16);
}

__global__ void detect_dtype(const u16* __restrict__ q, int* __restrict__ flag) {
    __shared__ int cnt;
    if (threadIdx.x == 0) cnt = 0;
    __syncthreads();
    int c = 0;
    for (int i = threadIdx.x; i < 16384; i += 256) {
        u16 x = q[i];
        if (((x >> 7) & 0xFF) == 0xFF) c++;
    }
    if (c) atomicAdd(&cnt, c);
    __syncthreads();
    if (threadIdx.x == 0) *flag = (cnt > 0) ? 1 : 0;
}

__device__ __forceinline__ void stage8_bf16(u16* dst, const u16* src) {
    *(uint4*)dst = *(const uint4*)src;
}
__device__ __forceinline__ void stage8_f32(u16* dst, const float* src) {
    float4 f0 = ((const float4*)src)[0];
    float4 f1 = ((const float4*)src)[1];
    ushort4 a = {f2bf(f0.x), f2bf(f0.y), f2bf(f0.z), f2bf(f0.w)};
    ushort4 b = {f2bf(f1.x), f2bf(f1.y), f2bf(f1.z), f2bf(f1.w)};
    *(ushort4*)dst = a;
    *(ushort4*)(dst + 4) = b;
}
__device__ __forceinline__ void stage16_bf16(u16* dst, const u16* src) {
    *(uint4*)dst = *(const uint4*)src;
    *(uint4*)(dst + 8) = *(const uint4*)(src + 8);
}
__device__ __forceinline__ void stage16_f32(u16* dst, const float* src) {
#pragma unroll
    for (int g = 0; g < 2; ++g) {
        float4 f0 = ((const float4*)src)[2 * g];
        float4 f1 = ((const float4*)src)[2 * g + 1];
        ushort4 a = {f2bf(f0.x), f2bf(f0.y), f2bf(f0.z), f2bf(f0.w)};
        ushort4 b = {f2bf(f1.x), f2bf(f1.y), f2bf(f1.z), f2bf(f1.w)};
        *(ushort4*)(dst + 8 * g) = a;
        *(ushort4*)(dst + 8 * g + 4) = b;
    }
}

// Fused Q/K/V projections. 128x64 tile, grid (64, 36); sel = by/12 picks
// which projection. 768 blocks per sel-slice -> 2304 blocks total (9/CU).
__global__ __launch_bounds__(256) void gemm_qkv(
    const void* __restrict__ Xq, const void* __restrict__ Xk, const void* __restrict__ Xv,
    const void* __restrict__ Wqp, const void* __restrict__ Wkp, const void* __restrict__ Wvp,
    const void* __restrict__ Bq, const void* __restrict__ Bk, const void* __restrict__ Bv,
    u16* __restrict__ Yq, u16* __restrict__ Yk, u16* __restrict__ Yv,
    const int* __restrict__ flag) {
    __shared__ __align__(16) u16 As[128][40];
    __shared__ __align__(16) u16 Bs[64][40];

    const int f32mode = *flag;
    const int by  = blockIdx.y;
    const int sel = by / 12;                 // 0=Q 1=K 2=V
    const int n0  = (by - sel * 12) * 64;
    const int m0  = blockIdx.x * 128;

    const void* Xp = sel == 0 ? Xq : (sel == 1 ? Xk : Xv);
    const void* Wp = sel == 0 ? Wqp : (sel == 1 ? Wkp : Wvp);
    const void* Bp = sel == 0 ? Bq : (sel == 1 ? Bk : Bv);
    u16* Y = sel == 0 ? Yq : (sel == 1 ? Yk : Yv);
    const float oscale = sel == 0 ? QSCALE : 1.0f;

    const int tid = threadIdx.x, lane = tid & 63, wave = tid >> 6;
    const int wr = (wave >> 1) * 64, wc = (wave & 1) * 32;
    const int l15 = lane & 15, quad = lane >> 4;

    const int srA = tid >> 1, scA = (tid & 1) * 16;
    const int srB = tid >> 2, scB = (tid & 3) * 8;

    f32x4 acc[4][2] = {};
    const size_t xoff = (size_t)(m0 + srA) * DM + scA;
    const size_t woff = (size_t)(n0 + srB) * DM + scB;

    for (int kb = 0; kb < DM; kb += 32) {
        if (f32mode) {
            stage16_f32(&As[srA][scA], (const float*)Xp + xoff + kb);
            stage8_f32(&Bs[srB][scB], (const float*)Wp + woff + kb);
        } else {
            stage16_bf16(&As[srA][scA], (const u16*)Xp + xoff + kb);
            stage8_bf16(&Bs[srB][scB], (const u16*)Wp + woff + kb);
        }
        __syncthreads();
        bf16x8 a[4], b[2];
#pragma unroll
        for (int i = 0; i < 4; ++i)
            a[i] = *(const bf16x8*)&As[wr + i * 16 + l15][quad * 8];
#pragma unroll
        for (int j = 0; j < 2; ++j)
            b[j] = *(const bf16x8*)&Bs[wc + j * 16 + l15][quad * 8];
#pragma unroll
        for (int i = 0; i < 4; ++i)
#pragma unroll
            for (int j = 0; j < 2; ++j)
                acc[i][j] = __builtin_amdgcn_mfma_f32_16x16x32_bf16(a[i], b[j], acc[i][j], 0, 0, 0);
        __syncthreads();
    }

#pragma unroll
    for (int j = 0; j < 2; ++j) {
        int o = n0 + wc + j * 16 + l15;
        float bv = f32mode ? ((const float*)Bp)[o] : bf2f(((const u16*)Bp)[o]);
#pragma unroll
        for (int i = 0; i < 4; ++i)
#pragma unroll
            for (int r = 0; r < 4; ++r) {
                int row = m0 + wr + i * 16 + quad * 4 + r;
                float val = (acc[i][j][r] + bv) * oscale;
                int bb = row >> 12, s = row & (SEQL - 1);
                int h = o >> 6, d = o & 63;
                if (sel < 2)
                    Y[((bb * HEADS + h) << 18) + (s << 6) + d] = f2bf(val);   // [b][h][s][d]
                else
                    Y[((bb * HEADS + h) << 18) + (d << 12) + s] = f2bf(val);  // [b][h][d][s]
            }
    }
}

// Output projection: ctx (bf16) @ Wo^T + bo. 128x64 tile, grid (64,12) = 768 = 3/CU.
__global__ __launch_bounds__(256) void gemm_out(const u16* __restrict__ X,
                                                const void* __restrict__ Wp,
                                                const void* __restrict__ Bp,
                                                void* __restrict__ Y,
                                                const int* __restrict__ flag) {
    __shared__ __align__(16) u16 As[128][40];
    __shared__ __align__(16) u16 Bs[64][40];

    const int f32mode = *flag;
    const int m0 = blockIdx.x * 128, n0 = blockIdx.y * 64;
    const int tid = threadIdx.x, lane = tid & 63, wave = tid >> 6;
    const int wr = (wave >> 1) * 64, wc = (wave & 1) * 32;
    const int l15 = lane & 15, quad = lane >> 4;
    const int srA = tid >> 1, scA = (tid & 1) * 16;
    const int srB = tid >> 2, scB = (tid & 3) * 8;

    f32x4 acc[4][2] = {};
    const size_t xoff = (size_t)(m0 + srA) * DM + scA;
    const size_t woff = (size_t)(n0 + srB) * DM + scB;

    for (int kb = 0; kb < DM; kb += 32) {
        stage16_bf16(&As[srA][scA], X + xoff + kb);
        if (f32mode) stage8_f32(&Bs[srB][scB], (const float*)Wp + woff + kb);
        else         stage8_bf16(&Bs[srB][scB], (const u16*)Wp + woff + kb);
        __syncthreads();
        bf16x8 a[4], b[2];
#pragma unroll
        for (int i = 0; i < 4; ++i)
            a[i] = *(const bf16x8*)&As[wr + i * 16 + l15][quad * 8];
#pragma unroll
        for (int j = 0; j < 2; ++j)
            b[j] = *(const bf16x8*)&Bs[wc + j * 16 + l15][quad * 8];
#pragma unroll
        for (int i = 0; i < 4; ++i)
#pragma unroll
            for (int j = 0; j < 2; ++j)
                acc[i][j] = __builtin_amdgcn_mfma_f32_16x16x32_bf16(a[i], b[j], acc[i][j], 0, 0, 0);
        __syncthreads();
    }

#pragma unroll
    for (int j = 0; j < 2; ++j) {
        int o = n0 + wc + j * 16 + l15;
        float bv = f32mode ? ((const float*)Bp)[o] : bf2f(((const u16*)Bp)[o]);
#pragma unroll
        for (int i = 0; i < 4; ++i)
#pragma unroll
            for (int r = 0; r < 4; ++r) {
                int row = m0 + wr + i * 16 + quad * 4 + r;
                float val = acc[i][j][r] + bv;
                if (f32mode) ((float*)Y)[(size_t)row * DM + o] = val;
                else         ((u16*)Y)[(size_t)row * DM + o] = f2bf(val);
            }
    }
}

// ---- flash v4: 32 q-rows per wave (128/block), K/V frags shared across qsubs ----
typedef __attribute__((address_space(1))) unsigned int glb_u32;
typedef __attribute__((address_space(3))) unsigned int lds_u32;

__device__ __forceinline__ void gld16(const u16* g, u16* l) {
    __builtin_amdgcn_global_load_lds((glb_u32*)g, (lds_u32*)l, 16, 0, 0);
}

__device__ __forceinline__ void stage_tile(const u16* gbase, int rstride,
                                           u16* lbase, int tid) {
#pragma unroll
    for (int it = 0; it < 2; ++it) {
        int c = it * 256 + tid;
        int row = c >> 3, p = c & 7;
        int gc = p ^ (row & 7);
        gld16(gbase + (size_t)row * rstride + gc * 8, lbase + c * 8);
    }
}

__global__ __launch_bounds__(256, 3) void flash_attn(const u16* __restrict__ Q,
                                                     const u16* __restrict__ K,
                                                     const u16* __restrict__ Vt,
                                                     const int* __restrict__ mask,
                                                     u16* __restrict__ ctx) {
    __shared__ __align__(16) u16 Ks[2][64 * 64];
    __shared__ __align__(16) u16 Vs[2][64 * 64];
    __shared__ __align__(16) float Ms[2][64];
    __shared__ __align__(16) u16 Ps[4][32 * 72];   // per-wave P^T/[out] [q0..31][kpos]

    const int tid  = threadIdx.x;
    const int lane = tid & 63;
    const int wave = tid >> 6;
    const int l15  = lane & 15;
    const int quad = lane >> 4;

    const int bh = blockIdx.y;
    const int b  = bh / HEADS;
    const int h  = bh - b * HEADS;
    const int qb = blockIdx.x * 128 + wave * 32;

    const u16* Qh = Q  + ((size_t)bh << 18);
    const u16* Kh = K  + ((size_t)bh << 18);
    const u16* Vh = Vt + ((size_t)bh << 18);
    const int* maskb = mask + b * SEQL;

    // Q B-operand fragments for two 16-row q-subtiles
    bf16x8 aq[2][2];
#pragma unroll
    for (int s = 0; s < 2; ++s)
#pragma unroll
        for (int c = 0; c < 2; ++c)
            aq[s][c] = *(const bf16x8*)&Qh[(size_t)(qb + s * 16 + l15) * DK + c * 32 + quad * 8];

    const int r7   = l15 & 7;
    const int ck0  = (quad ^ r7) * 8;
    const int ck1  = ((quad + 4) ^ r7) * 8;
    const int lrow = l15 * 64;

    float m_s[2] = {-3.0e38f, -3.0e38f}, l_s[2] = {0.f, 0.f};
    f32x4 o_acc[2][4] = {};

    int mreg = 0;
    if (tid < 64) mreg = maskb[tid];
    stage_tile(Kh, DK, &Ks[0][0], tid);
    stage_tile(Vh, SEQL, &Vs[0][0], tid);
    if (tid < 64) {
        Ms[0][tid] = (mreg == 0) ? -1.0e9f : 0.0f;
        mreg = maskb[64 + tid];
    }
    __syncthreads();

    for (int t = 0; t < 64; ++t) {
        const int cur = t & 1, nxt = cur ^ 1;
        if (t < 63) {
            const int kt = (t + 1) * 64;
            stage_tile(Kh + (size_t)kt * DK, DK, &Ks[nxt][0], tid);
            stage_tile(Vh + kt, SEQL, &Vs[nxt][0], tid);
            if (tid < 64) {
                Ms[nxt][tid] = (mreg == 0) ? -1.0e9f : 0.0f;
                if (t < 62) mreg = maskb[(t + 2) * 64 + tid];
            }
        }

        const u16* kb = &Ks[cur][0];
        const u16* vb = &Vs[cur][0];

        // S^T (base-2 units): lane owns q = s*16 + l15, kpos = nt*16 + quad*4 + r
        f32x4 s4[2][4];
#pragma unroll
        for (int nt = 0; nt < 4; ++nt) {
            bf16x8 ak0 = *(const bf16x8*)&kb[lrow + nt * 1024 + ck0];
            bf16x8 ak1 = *(const bf16x8*)&kb[lrow + nt * 1024 + ck1];
            f32x4 bias = *(const f32x4*)&Ms[cur][nt * 16 + quad * 4];
#pragma unroll
            for (int s = 0; s < 2; ++s) {
                f32x4 z = {};
                z = __builtin_amdgcn_mfma_f32_16x16x32_bf16(ak0, aq[s][0], z, 0, 0, 0);
                z = __builtin_amdgcn_mfma_f32_16x16x32_bf16(ak1, aq[s][1], z, 0, 0, 0);
#pragma unroll
                for (int r = 0; r < 4; ++r) s4[s][nt][r] = z[r] + bias[r];
            }
        }

        float newm[2], rs[2];
#pragma unroll
        for (int s = 0; s < 2; ++s) {
            float mx = -3.0e38f;
#pragma unroll
            for (int nt = 0; nt < 4; ++nt)
#pragma unroll
                for (int r = 0; r < 4; ++r) mx = fmaxf(mx, s4[s][nt][r]);
            mx = fmaxf(mx, __shfl_xor(mx, 16, 64));
            mx = fmaxf(mx, __shfl_xor(mx, 32, 64));
            newm[s] = fmaxf(m_s[s], mx);

            float r2 = 0.f;
#pragma unroll
            for (int nt = 0; nt < 4; ++nt)
#pragma unroll
                for (int r = 0; r < 4; ++r) {
                    float p = EXP2F(s4[s][nt][r] - newm[s]);
                    s4[s][nt][r] = p;
                    r2 += p;
                }
            r2 += __shfl_xor(r2, 16, 64);
            r2 += __shfl_xor(r2, 32, 64);
            rs[s] = r2;
        }

        if (!__all(newm[0] == m_s[0] && newm[1] == m_s[1])) {
#pragma unroll
            for (int s = 0; s < 2; ++s) {
                float alpha = EXP2F(m_s[s] - newm[s]);
                l_s[s] *= alpha;
#pragma unroll
                for (int dv = 0; dv < 4; ++dv)
#pragma unroll
                    for (int r = 0; r < 4; ++r) o_acc[s][dv][r] *= alpha;
                m_s[s] = newm[s];
            }
        }
        l_s[0] += rs[0];
        l_s[1] += rs[1];

        // P^T into per-wave LDS (wave-private; compiler fence orders write->read)
#pragma unroll
        for (int s = 0; s < 2; ++s)
#pragma unroll
            for (int nt = 0; nt < 4; ++nt) {
                union { __hip_bfloat162 h2[2]; uint2 u; } cv;
                cv.h2[0] = __float22bfloat162_rn(make_float2(s4[s][nt][0], s4[s][nt][1]));
                cv.h2[1] = __float22bfloat162_rn(make_float2(s4[s][nt][2], s4[s][nt][3]));
                *(uint2*)&Ps[wave][(s * 16 + l15) * 72 + nt * 16 + quad * 4] = cv.u;
            }
        asm volatile("" ::: "memory");

        bf16x8 bp[2][2];
#pragma unroll
        for (int s = 0; s < 2; ++s)
#pragma unroll
            for (int c = 0; c < 2; ++c)
                bp[s][c] = *(const bf16x8*)&Ps[wave][(s * 16 + l15) * 72 + c * 32 + quad * 8];

#pragma unroll
        for (int dv = 0; dv < 4; ++dv) {
            bf16x8 av0 = *(const bf16x8*)&vb[lrow + dv * 1024 + ck0];
            bf16x8 av1 = *(const bf16x8*)&vb[lrow + dv * 1024 + ck1];
#pragma unroll
            for (int s = 0; s < 2; ++s) {
                o_acc[s][dv] = __builtin_amdgcn_mfma_f32_16x16x32_bf16(av0, bp[s][0], o_acc[s][dv], 0, 0, 0);
                o_acc[s][dv] = __builtin_amdgcn_mfma_f32_16x16x32_bf16(av1, bp[s][1], o_acc[s][dv], 0, 0, 0);
            }
        }
        __syncthreads();
    }

    // epilogue: normalize, transpose through Ps, coalesced store
#pragma unroll
    for (int s = 0; s < 2; ++s) {
        float inv = 1.0f / l_s[s];
#pragma unroll
        for (int dv = 0; dv < 4; ++dv) {
            union { __hip_bfloat162 h2[2]; uint2 u; } cv;
            cv.h2[0] = __float22bfloat162_rn(make_float2(o_acc[s][dv][0] * inv, o_acc[s][dv][1] * inv));
            cv.h2[1] = __float22bfloat162_rn(make_float2(o_acc[s][dv][2] * inv, o_acc[s][dv][3] * inv));
            *(uint2*)&Ps[wave][(s * 16 + l15) * 72 + dv * 16 + quad * 4] = cv.u;
        }
    }
    asm volatile("" ::: "memory");
    {
        int rowq = lane >> 2, dchunk = lane & 3;
#pragma unroll
        for (int s = 0; s < 2; ++s) {
            uint4 w0 = *(const uint4*)&Ps[wave][(s * 16 + rowq) * 72 + dchunk * 16];
            uint4 w1 = *(const uint4*)&Ps[wave][(s * 16 + rowq) * 72 + dchunk * 16 + 8];
            size_t orow = (size_t)(b * SEQL + qb + s * 16 + rowq) * DM + h * DK + dchunk * 16;
            *(uint4*)&ctx[orow] = w0;
            *(uint4*)&ctx[orow + 8] = w1;
        }
    }
}

extern "C" void kernel_launch(void* const* d_in, const int* in_sizes, int n_in,
                              void* d_out, int out_size, void* d_ws, size_t ws_size,
                              hipStream_t stream) {
    const void* q   = d_in[0];
    const void* k   = d_in[1];
    const void* v   = d_in[2];
    const void* Wq  = d_in[3];
    const void* bq  = d_in[4];
    const void* Wk  = d_in[5];
    const void* bk  = d_in[6];
    const void* Wv  = d_in[7];
    const void* bv  = d_in[8];
    const void* Wo  = d_in[9];
    const void* bo  = d_in[10];
    const int* mask = (const int*)d_in[11];

    const size_t NSH = (size_t)BSZ * HEADS * SEQL * DK;
    const size_t need = 4 * NSH * sizeof(u16) + 256;
    if (ws_size < need) return;

    u16* ws  = (u16*)d_ws;
    u16* Qh  = ws;
    u16* Kh  = ws + NSH;
    u16* Vth = ws + 2 * NSH;
    u16* ctx = ws + 3 * NSH;
    int* dflag = (int*)((char*)d_ws + 4 * NSH * sizeof(u16));

    detect_dtype<<<1, 256, 0, stream>>>((const u16*)q, dflag);

    gemm_qkv<<<dim3(MROWS / 128, 36), 256, 0, stream>>>(
        q, k, v, Wq, Wk, Wv, bq, bk, bv, Qh, Kh, Vth, dflag);
    flash_attn<<<dim3(SEQL / 128, BSZ * HEADS), 256, 0, stream>>>(Qh, Kh, Vth, mask, ctx);
    gemm_out<<<dim3(MROWS / 128, 12), 256, 0, stream>>>(ctx, Wo, bo, d_out, dflag);
}

// Round 8
// 437.606 us; speedup vs baseline: 1.1994x; 1.0166x over previous
//
#include <hip/hip_runtime.h>
#include <hip/hip_bf16.h>

typedef __bf16 bf16x8 __attribute__((ext_vector_type(8)));
typedef float f32x4 __attribute__((ext_vector_type(4)));
typedef unsigned short u16;

#define HEADS 12
#define DK 64
#define DM 768
#define SEQL 4096
#define BSZ 2
#define MROWS (BSZ * SEQL) /* 8192 */
#define WELEM (DM * DM)    /* 589824 */

// 1/sqrt(64) * log2(e): folded into Q projection so flash softmax runs base-2.
#define QSCALE 0.180336880434245f
#define EXP2F(x) __builtin_amdgcn_exp2f(x)

__device__ __forceinline__ float bf2f(u16 x) {
    unsigned int u = ((unsigned int)x) << 16;
    return __uint_as_float(u);
}
__device__ __forceinline__ u16 f2bf(float f) {
    unsigned int u = __float_as_uint(f);
    u += 0x7fff + ((u >> 16) & 1);
    return (u16)(u >> 16);
}
// packed f32x2 -> bf16x2 (single v_cvt_pk_bf16_f32 on gfx950)
__device__ __forceinline__ unsigned int cvt_pk(float lo, float hi) {
#if __has_builtin(__builtin_amdgcn_cvt_pk_bf16_f32)
    auto r = __builtin_amdgcn_cvt_pk_bf16_f32(lo, hi);
    unsigned int u;
    __builtin_memcpy(&u, &r, 4);
    return u;
#else
    return (unsigned int)f2bf(lo) | ((unsigned int)f2bf(hi) << 16);
#endif
}

__global__ void detect_dtype(const u16* __restrict__ q, int* __restrict__ flag) {
    __shared__ int cnt;
    if (threadIdx.x == 0) cnt = 0;
    __syncthreads();
    int c = 0;
    for (int i = threadIdx.x; i < 16384; i += 256) {
        u16 x = q[i];
        if (((x >> 7) & 0xFF) == 0xFF) c++;
    }
    if (c) atomicAdd(&cnt, c);
    __syncthreads();
    if (threadIdx.x == 0) *flag = (cnt > 0) ? 1 : 0;
}

// One-shot conversion of the 4 weight matrices + 4 biases to bf16 workspace.
#define WTOT (4 * WELEM)
#define BTOT (4 * 768)
__global__ __launch_bounds__(256) void convert_wb(
    const void* __restrict__ W0, const void* __restrict__ W1,
    const void* __restrict__ W2, const void* __restrict__ W3,
    const void* __restrict__ B0, const void* __restrict__ B1,
    const void* __restrict__ B2, const void* __restrict__ B3,
    u16* __restrict__ Wc, u16* __restrict__ bc, const int* __restrict__ flag) {
    const int f32m = *flag;
    int i4 = blockIdx.x * 256 + threadIdx.x;
    const int n4 = (WTOT + BTOT) / 4;
    if (i4 >= n4) return;
    int base = i4 * 4;
    const void* src;
    u16* dst;
    int off;
    if (base < WTOT) {
        int w = base / WELEM;
        off = base - w * WELEM;
        src = (w == 0) ? W0 : (w == 1) ? W1 : (w == 2) ? W2 : W3;
        dst = Wc + w * WELEM + off;
    } else {
        int bi = base - WTOT;
        int w = bi / 768;
        off = bi - w * 768;
        src = (w == 0) ? B0 : (w == 1) ? B1 : (w == 2) ? B2 : B3;
        dst = bc + w * 768 + off;
    }
    if (f32m) {
        float4 f = *(const float4*)((const float*)src + off);
        uint2 p = {cvt_pk(f.x, f.y), cvt_pk(f.z, f.w)};
        *(uint2*)dst = p;
    } else {
        *(uint2*)dst = *(const uint2*)((const u16*)src + off);
    }
}

__device__ __forceinline__ void stage8_bf16(u16* dst, const u16* src) {
    *(uint4*)dst = *(const uint4*)src;
}
__device__ __forceinline__ void stage16_bf16(u16* dst, const u16* src) {
    *(uint4*)dst = *(const uint4*)src;
    *(uint4*)(dst + 8) = *(const uint4*)(src + 8);
}
// 16 f32 -> 16 bf16 via 8 packed cvts + 2 b128 LDS writes
__device__ __forceinline__ void stage16_f32pk(u16* dst, const float* src) {
    float4 f0 = ((const float4*)src)[0];
    float4 f1 = ((const float4*)src)[1];
    float4 f2 = ((const float4*)src)[2];
    float4 f3 = ((const float4*)src)[3];
    uint4 lo = {cvt_pk(f0.x, f0.y), cvt_pk(f0.z, f0.w), cvt_pk(f1.x, f1.y), cvt_pk(f1.z, f1.w)};
    uint4 hi = {cvt_pk(f2.x, f2.y), cvt_pk(f2.z, f2.w), cvt_pk(f3.x, f3.y), cvt_pk(f3.z, f3.w)};
    *(uint4*)dst = lo;
    *(uint4*)(dst + 8) = hi;
}

// Fused Q/K/V projections. 128x64 tile, grid (64, 36); sel = by/12.
// Weights/biases read from pre-converted bf16 (Wc/bc).
__global__ __launch_bounds__(256) void gemm_qkv(
    const void* __restrict__ Xq, const void* __restrict__ Xk, const void* __restrict__ Xv,
    const u16* __restrict__ Wc, const u16* __restrict__ bc,
    u16* __restrict__ Yq, u16* __restrict__ Yk, u16* __restrict__ Yv,
    const int* __restrict__ flag) {
    __shared__ __align__(16) u16 As[128][40];
    __shared__ __align__(16) u16 Bs[64][40];

    const int f32mode = *flag;
    const int by  = blockIdx.y;
    const int sel = by / 12;                 // 0=Q 1=K 2=V
    const int n0  = (by - sel * 12) * 64;
    const int m0  = blockIdx.x * 128;

    const void* Xp = sel == 0 ? Xq : (sel == 1 ? Xk : Xv);
    const u16* Wp = Wc + sel * WELEM;
    const u16* Bp = bc + sel * 768;
    u16* Y = sel == 0 ? Yq : (sel == 1 ? Yk : Yv);
    const float oscale = sel == 0 ? QSCALE : 1.0f;

    const int tid = threadIdx.x, lane = tid & 63, wave = tid >> 6;
    const int wr = (wave >> 1) * 64, wc = (wave & 1) * 32;
    const int l15 = lane & 15, quad = lane >> 4;

    const int srA = tid >> 1, scA = (tid & 1) * 16;
    const int srB = tid >> 2, scB = (tid & 3) * 8;

    f32x4 acc[4][2] = {};
    const size_t xoff = (size_t)(m0 + srA) * DM + scA;
    const size_t woff = (size_t)(n0 + srB) * DM + scB;

    for (int kb = 0; kb < DM; kb += 32) {
        if (f32mode) stage16_f32pk(&As[srA][scA], (const float*)Xp + xoff + kb);
        else         stage16_bf16(&As[srA][scA], (const u16*)Xp + xoff + kb);
        stage8_bf16(&Bs[srB][scB], Wp + woff + kb);
        __syncthreads();
        bf16x8 a[4], b[2];
#pragma unroll
        for (int i = 0; i < 4; ++i)
            a[i] = *(const bf16x8*)&As[wr + i * 16 + l15][quad * 8];
#pragma unroll
        for (int j = 0; j < 2; ++j)
            b[j] = *(const bf16x8*)&Bs[wc + j * 16 + l15][quad * 8];
#pragma unroll
        for (int i = 0; i < 4; ++i)
#pragma unroll
            for (int j = 0; j < 2; ++j)
                acc[i][j] = __builtin_amdgcn_mfma_f32_16x16x32_bf16(a[i], b[j], acc[i][j], 0, 0, 0);
        __syncthreads();
    }

#pragma unroll
    for (int j = 0; j < 2; ++j) {
        int o = n0 + wc + j * 16 + l15;
        float bv = bf2f(Bp[o]);
#pragma unroll
        for (int i = 0; i < 4; ++i)
#pragma unroll
            for (int r = 0; r < 4; ++r) {
                int row = m0 + wr + i * 16 + quad * 4 + r;
                float val = (acc[i][j][r] + bv) * oscale;
                int bb = row >> 12, s = row & (SEQL - 1);
                int h = o >> 6, d = o & 63;
                if (sel < 2)
                    Y[((bb * HEADS + h) << 18) + (s << 6) + d] = f2bf(val);   // [b][h][s][d]
                else
                    Y[((bb * HEADS + h) << 18) + (d << 12) + s] = f2bf(val);  // [b][h][d][s]
            }
    }
}

// Output projection: ctx (bf16) @ Wo^T + bo. 128x64 tile, grid (64,12).
__global__ __launch_bounds__(256) void gemm_out(const u16* __restrict__ X,
                                                const u16* __restrict__ Wp,
                                                const u16* __restrict__ Bp,
                                                void* __restrict__ Y,
                                                const int* __restrict__ flag) {
    __shared__ __align__(16) u16 As[128][40];
    __shared__ __align__(16) u16 Bs[64][40];

    const int f32mode = *flag;
    const int m0 = blockIdx.x * 128, n0 = blockIdx.y * 64;
    const int tid = threadIdx.x, lane = tid & 63, wave = tid >> 6;
    const int wr = (wave >> 1) * 64, wc = (wave & 1) * 32;
    const int l15 = lane & 15, quad = lane >> 4;
    const int srA = tid >> 1, scA = (tid & 1) * 16;
    const int srB = tid >> 2, scB = (tid & 3) * 8;

    f32x4 acc[4][2] = {};
    const size_t xoff = (size_t)(m0 + srA) * DM + scA;
    const size_t woff = (size_t)(n0 + srB) * DM + scB;

    for (int kb = 0; kb < DM; kb += 32) {
        stage16_bf16(&As[srA][scA], X + xoff + kb);
        stage8_bf16(&Bs[srB][scB], Wp + woff + kb);
        __syncthreads();
        bf16x8 a[4], b[2];
#pragma unroll
        for (int i = 0; i < 4; ++i)
            a[i] = *(const bf16x8*)&As[wr + i * 16 + l15][quad * 8];
#pragma unroll
        for (int j = 0; j < 2; ++j)
            b[j] = *(const bf16x8*)&Bs[wc + j * 16 + l15][quad * 8];
#pragma unroll
        for (int i = 0; i < 4; ++i)
#pragma unroll
            for (int j = 0; j < 2; ++j)
                acc[i][j] = __builtin_amdgcn_mfma_f32_16x16x32_bf16(a[i], b[j], acc[i][j], 0, 0, 0);
        __syncthreads();
    }

#pragma unroll
    for (int j = 0; j < 2; ++j) {
        int o = n0 + wc + j * 16 + l15;
        float bv = bf2f(Bp[o]);
#pragma unroll
        for (int i = 0; i < 4; ++i)
#pragma unroll
            for (int r = 0; r < 4; ++r) {
                int row = m0 + wr + i * 16 + quad * 4 + r;
                float val = acc[i][j][r] + bv;
                if (f32mode) ((float*)Y)[(size_t)row * DM + o] = val;
                else         ((u16*)Y)[(size_t)row * DM + o] = f2bf(val);
            }
    }
}

// ---- flash v4 (unchanged from R7: 32 q-rows/wave, shared K/V frags) ----
typedef __attribute__((address_space(1))) unsigned int glb_u32;
typedef __attribute__((address_space(3))) unsigned int lds_u32;

__device__ __forceinline__ void gld16(const u16* g, u16* l) {
    __builtin_amdgcn_global_load_lds((glb_u32*)g, (lds_u32*)l, 16, 0, 0);
}

__device__ __forceinline__ void stage_tile(const u16* gbase, int rstride,
                                           u16* lbase, int tid) {
#pragma unroll
    for (int it = 0; it < 2; ++it) {
        int c = it * 256 + tid;
        int row = c >> 3, p = c & 7;
        int gc = p ^ (row & 7);
        gld16(gbase + (size_t)row * rstride + gc * 8, lbase + c * 8);
    }
}

__global__ __launch_bounds__(256, 3) void flash_attn(const u16* __restrict__ Q,
                                                     const u16* __restrict__ K,
                                                     const u16* __restrict__ Vt,
                                                     const int* __restrict__ mask,
                                                     u16* __restrict__ ctx) {
    __shared__ __align__(16) u16 Ks[2][64 * 64];
    __shared__ __align__(16) u16 Vs[2][64 * 64];
    __shared__ __align__(16) float Ms[2][64];
    __shared__ __align__(16) u16 Ps[4][32 * 72];

    const int tid  = threadIdx.x;
    const int lane = tid & 63;
    const int wave = tid >> 6;
    const int l15  = lane & 15;
    const int quad = lane >> 4;

    const int bh = blockIdx.y;
    const int b  = bh / HEADS;
    const int h  = bh - b * HEADS;
    const int qb = blockIdx.x * 128 + wave * 32;

    const u16* Qh = Q  + ((size_t)bh << 18);
    const u16* Kh = K  + ((size_t)bh << 18);
    const u16* Vh = Vt + ((size_t)bh << 18);
    const int* maskb = mask + b * SEQL;

    bf16x8 aq[2][2];
#pragma unroll
    for (int s = 0; s < 2; ++s)
#pragma unroll
        for (int c = 0; c < 2; ++c)
            aq[s][c] = *(const bf16x8*)&Qh[(size_t)(qb + s * 16 + l15) * DK + c * 32 + quad * 8];

    const int r7   = l15 & 7;
    const int ck0  = (quad ^ r7) * 8;
    const int ck1  = ((quad + 4) ^ r7) * 8;
    const int lrow = l15 * 64;

    float m_s[2] = {-3.0e38f, -3.0e38f}, l_s[2] = {0.f, 0.f};
    f32x4 o_acc[2][4] = {};

    int mreg = 0;
    if (tid < 64) mreg = maskb[tid];
    stage_tile(Kh, DK, &Ks[0][0], tid);
    stage_tile(Vh, SEQL, &Vs[0][0], tid);
    if (tid < 64) {
        Ms[0][tid] = (mreg == 0) ? -1.0e9f : 0.0f;
        mreg = maskb[64 + tid];
    }
    __syncthreads();

    for (int t = 0; t < 64; ++t) {
        const int cur = t & 1, nxt = cur ^ 1;
        if (t < 63) {
            const int kt = (t + 1) * 64;
            stage_tile(Kh + (size_t)kt * DK, DK, &Ks[nxt][0], tid);
            stage_tile(Vh + kt, SEQL, &Vs[nxt][0], tid);
            if (tid < 64) {
                Ms[nxt][tid] = (mreg == 0) ? -1.0e9f : 0.0f;
                if (t < 62) mreg = maskb[(t + 2) * 64 + tid];
            }
        }

        const u16* kb = &Ks[cur][0];
        const u16* vb = &Vs[cur][0];

        f32x4 s4[2][4];
#pragma unroll
        for (int nt = 0; nt < 4; ++nt) {
            bf16x8 ak0 = *(const bf16x8*)&kb[lrow + nt * 1024 + ck0];
            bf16x8 ak1 = *(const bf16x8*)&kb[lrow + nt * 1024 + ck1];
            f32x4 bias = *(const f32x4*)&Ms[cur][nt * 16 + quad * 4];
#pragma unroll
            for (int s = 0; s < 2; ++s) {
                f32x4 z = {};
                z = __builtin_amdgcn_mfma_f32_16x16x32_bf16(ak0, aq[s][0], z, 0, 0, 0);
                z = __builtin_amdgcn_mfma_f32_16x16x32_bf16(ak1, aq[s][1], z, 0, 0, 0);
#pragma unroll
                for (int r = 0; r < 4; ++r) s4[s][nt][r] = z[r] + bias[r];
            }
        }

        float newm[2], rs[2];
#pragma unroll
        for (int s = 0; s < 2; ++s) {
            float mx = -3.0e38f;
#pragma unroll
            for (int nt = 0; nt < 4; ++nt)
#pragma unroll
                for (int r = 0; r < 4; ++r) mx = fmaxf(mx, s4[s][nt][r]);
            mx = fmaxf(mx, __shfl_xor(mx, 16, 64));
            mx = fmaxf(mx, __shfl_xor(mx, 32, 64));
            newm[s] = fmaxf(m_s[s], mx);

            float r2 = 0.f;
#pragma unroll
            for (int nt = 0; nt < 4; ++nt)
#pragma unroll
                for (int r = 0; r < 4; ++r) {
                    float p = EXP2F(s4[s][nt][r] - newm[s]);
                    s4[s][nt][r] = p;
                    r2 += p;
                }
            r2 += __shfl_xor(r2, 16, 64);
            r2 += __shfl_xor(r2, 32, 64);
            rs[s] = r2;
        }

        if (!__all(newm[0] == m_s[0] && newm[1] == m_s[1])) {
#pragma unroll
            for (int s = 0; s < 2; ++s) {
                float alpha = EXP2F(m_s[s] - newm[s]);
                l_s[s] *= alpha;
#pragma unroll
                for (int dv = 0; dv < 4; ++dv)
#pragma unroll
                    for (int r = 0; r < 4; ++r) o_acc[s][dv][r] *= alpha;
                m_s[s] = newm[s];
            }
        }
        l_s[0] += rs[0];
        l_s[1] += rs[1];

#pragma unroll
        for (int s = 0; s < 2; ++s)
#pragma unroll
            for (int nt = 0; nt < 4; ++nt) {
                uint2 cv = {cvt_pk(s4[s][nt][0], s4[s][nt][1]),
                            cvt_pk(s4[s][nt][2], s4[s][nt][3])};
                *(uint2*)&Ps[wave][(s * 16 + l15) * 72 + nt * 16 + quad * 4] = cv;
            }
        asm volatile("" ::: "memory");

        bf16x8 bp[2][2];
#pragma unroll
        for (int s = 0; s < 2; ++s)
#pragma unroll
            for (int c = 0; c < 2; ++c)
                bp[s][c] = *(const bf16x8*)&Ps[wave][(s * 16 + l15) * 72 + c * 32 + quad * 8];

#pragma unroll
        for (int dv = 0; dv < 4; ++dv) {
            bf16x8 av0 = *(const bf16x8*)&vb[lrow + dv * 1024 + ck0];
            bf16x8 av1 = *(const bf16x8*)&vb[lrow + dv * 1024 + ck1];
#pragma unroll
            for (int s = 0; s < 2; ++s) {
                o_acc[s][dv] = __builtin_amdgcn_mfma_f32_16x16x32_bf16(av0, bp[s][0], o_acc[s][dv], 0, 0, 0);
                o_acc[s][dv] = __builtin_amdgcn_mfma_f32_16x16x32_bf16(av1, bp[s][1], o_acc[s][dv], 0, 0, 0);
            }
        }
        __syncthreads();
    }

#pragma unroll
    for (int s = 0; s < 2; ++s) {
        float inv = 1.0f / l_s[s];
#pragma unroll
        for (int dv = 0; dv < 4; ++dv) {
            uint2 cv = {cvt_pk(o_acc[s][dv][0] * inv, o_acc[s][dv][1] * inv),
                        cvt_pk(o_acc[s][dv][2] * inv, o_acc[s][dv][3] * inv)};
            *(uint2*)&Ps[wave][(s * 16 + l15) * 72 + dv * 16 + quad * 4] = cv;
        }
    }
    asm volatile("" ::: "memory");
    {
        int rowq = lane >> 2, dchunk = lane & 3;
#pragma unroll
        for (int s = 0; s < 2; ++s) {
            uint4 w0 = *(const uint4*)&Ps[wave][(s * 16 + rowq) * 72 + dchunk * 16];
            uint4 w1 = *(const uint4*)&Ps[wave][(s * 16 + rowq) * 72 + dchunk * 16 + 8];
            size_t orow = (size_t)(b * SEQL + qb + s * 16 + rowq) * DM + h * DK + dchunk * 16;
            *(uint4*)&ctx[orow] = w0;
            *(uint4*)&ctx[orow + 8] = w1;
        }
    }
}

extern "C" void kernel_launch(void* const* d_in, const int* in_sizes, int n_in,
                              void* d_out, int out_size, void* d_ws, size_t ws_size,
                              hipStream_t stream) {
    const void* q   = d_in[0];
    const void* k   = d_in[1];
    const void* v   = d_in[2];
    const void* Wq  = d_in[3];
    const void* bq  = d_in[4];
    const void* Wk  = d_in[5];
    const void* bk  = d_in[6];
    const void* Wv  = d_in[7];
    const void* bv  = d_in[8];
    const void* Wo  = d_in[9];
    const void* bo  = d_in[10];
    const int* mask = (const int*)d_in[11];

    const size_t NSH = (size_t)BSZ * HEADS * SEQL * DK;     // 6291456
    const size_t WS_W = 4 * NSH;                            // Wc offset (u16)
    const size_t WS_B = WS_W + 4 * (size_t)WELEM;           // bc offset
    const size_t WS_F = WS_B + 4 * 768;                     // dflag offset
    const size_t need = WS_F * sizeof(u16) + 64;
    if (ws_size < need) return;

    u16* ws  = (u16*)d_ws;
    u16* Qh  = ws;
    u16* Kh  = ws + NSH;
    u16* Vth = ws + 2 * NSH;
    u16* ctx = ws + 3 * NSH;
    u16* Wc  = ws + WS_W;
    u16* bc  = ws + WS_B;
    int* dflag = (int*)(ws + WS_F);

    detect_dtype<<<1, 256, 0, stream>>>((const u16*)q, dflag);
    convert_wb<<<((WTOT + BTOT) / 4 + 255) / 256, 256, 0, stream>>>(
        Wq, Wk, Wv, Wo, bq, bk, bv, bo, Wc, bc, dflag);

    gemm_qkv<<<dim3(MROWS / 128, 36), 256, 0, stream>>>(
        q, k, v, Wc, bc, Qh, Kh, Vth, dflag);
    flash_attn<<<dim3(SEQL / 128, BSZ * HEADS), 256, 0, stream>>>(Qh, Kh, Vth, mask, ctx);
    gemm_out<<<dim3(MROWS / 128, 12), 256, 0, stream>>>(ctx, Wc + 3 * (size_t)WELEM,
                                                        bc + 3 * 768, d_out, dflag);
}

// Round 9
// 408.316 us; speedup vs baseline: 1.2855x; 1.0717x over previous
//
#include <hip/hip_runtime.h>
#include <hip/hip_bf16.h>

typedef __bf16 bf16x8 __attribute__((ext_vector_type(8)));
typedef float f32x4 __attribute__((ext_vector_type(4)));
typedef unsigned short u16;

#define HEADS 12
#define DK 64
#define DM 768
#define SEQL 4096
#define BSZ 2
#define MROWS (BSZ * SEQL) /* 8192 */
#define WELEM (DM * DM)    /* 589824 */
#define NX 6291456         /* MROWS*DM == BSZ*HEADS*SEQL*DK */
#define WTOT (4 * WELEM)
#define BTOT (4 * 768)

// 1/sqrt(64) * log2(e): folded into Q projection so flash softmax runs base-2.
#define QSCALE 0.180336880434245f
#define EXP2F(x) __builtin_amdgcn_exp2f(x)

__device__ __forceinline__ float bf2f(u16 x) {
    unsigned int u = ((unsigned int)x) << 16;
    return __uint_as_float(u);
}
__device__ __forceinline__ u16 f2bf(float f) {
    unsigned int u = __float_as_uint(f);
    u += 0x7fff + ((u >> 16) & 1);
    return (u16)(u >> 16);
}
__device__ __forceinline__ unsigned int cvt_pk(float lo, float hi) {
#if __has_builtin(__builtin_amdgcn_cvt_pk_bf16_f32)
    auto r = __builtin_amdgcn_cvt_pk_bf16_f32(lo, hi);
    unsigned int u;
    __builtin_memcpy(&u, &r, 4);
    return u;
#else
    return (unsigned int)f2bf(lo) | ((unsigned int)f2bf(hi) << 16);
#endif
}

__global__ void detect_dtype(const u16* __restrict__ q, int* __restrict__ flag) {
    __shared__ int cnt;
    if (threadIdx.x == 0) cnt = 0;
    __syncthreads();
    int c = 0;
    for (int i = threadIdx.x; i < 16384; i += 256) {
        u16 x = q[i];
        if (((x >> 7) & 0xFF) == 0xFF) c++;
    }
    if (c) atomicAdd(&cnt, c);
    __syncthreads();
    if (threadIdx.x == 0) *flag = (cnt > 0) ? 1 : 0;
}

// Convert q,k,v inputs (3 x NX elems) to bf16 workspace. 8 elems/thread.
__global__ __launch_bounds__(256) void convert_x(
    const void* __restrict__ X0, const void* __restrict__ X1, const void* __restrict__ X2,
    u16* __restrict__ Xc, const int* __restrict__ flag) {
    const int f32m = *flag;
    int i8 = blockIdx.x * 256 + threadIdx.x;
    if (i8 >= 3 * NX / 8) return;
    int w = i8 / (NX / 8);
    int off8 = i8 - w * (NX / 8);
    const void* src = (w == 0) ? X0 : (w == 1) ? X1 : X2;
    u16* dst = Xc + (size_t)w * NX + (size_t)off8 * 8;
    if (f32m) {
        float4 f0 = ((const float4*)src)[off8 * 2];
        float4 f1 = ((const float4*)src)[off8 * 2 + 1];
        uint4 p = {cvt_pk(f0.x, f0.y), cvt_pk(f0.z, f0.w),
                   cvt_pk(f1.x, f1.y), cvt_pk(f1.z, f1.w)};
        *(uint4*)dst = p;
    } else {
        *(uint4*)dst = ((const uint4*)src)[off8];
    }
}

// One-shot conversion of the 4 weight matrices + 4 biases to bf16 workspace.
__global__ __launch_bounds__(256) void convert_wb(
    const void* __restrict__ W0, const void* __restrict__ W1,
    const void* __restrict__ W2, const void* __restrict__ W3,
    const void* __restrict__ B0, const void* __restrict__ B1,
    const void* __restrict__ B2, const void* __restrict__ B3,
    u16* __restrict__ Wc, u16* __restrict__ bc, const int* __restrict__ flag) {
    const int f32m = *flag;
    int i4 = blockIdx.x * 256 + threadIdx.x;
    const int n4 = (WTOT + BTOT) / 4;
    if (i4 >= n4) return;
    int base = i4 * 4;
    const void* src;
    u16* dst;
    int off;
    if (base < WTOT) {
        int w = base / WELEM;
        off = base - w * WELEM;
        src = (w == 0) ? W0 : (w == 1) ? W1 : (w == 2) ? W2 : W3;
        dst = Wc + w * WELEM + off;
    } else {
        int bi = base - WTOT;
        int w = bi / 768;
        off = bi - w * 768;
        src = (w == 0) ? B0 : (w == 1) ? B1 : (w == 2) ? B2 : B3;
        dst = bc + w * 768 + off;
    }
    if (f32m) {
        float4 f = *(const float4*)((const float*)src + off);
        uint2 p = {cvt_pk(f.x, f.y), cvt_pk(f.z, f.w)};
        *(uint2*)dst = p;
    } else {
        *(uint2*)dst = *(const uint2*)((const u16*)src + off);
    }
}

// ---- async staging helpers ----
typedef __attribute__((address_space(1))) unsigned int glb_u32;
typedef __attribute__((address_space(3))) unsigned int lds_u32;

__device__ __forceinline__ void gld16(const u16* g, u16* l) {
    __builtin_amdgcn_global_load_lds((glb_u32*)g, (lds_u32*)l, 16, 0, 0);
}

// Stage a R-row x 32-col bf16 tile (row stride DM) into LDS via global_load_lds.
// 4 chunks of 16B per row; XOR swizzle: LDS chunk (row,p) <- global (row, p^(row&3)).
template <int NCH>  // total 16B chunks = R*4 ; NCH/256 per thread
__device__ __forceinline__ void stage_g(const u16* gbase, u16* lbase, int tid) {
#pragma unroll
    for (int it = 0; it < NCH / 256; ++it) {
        int c = it * 256 + tid;
        int row = c >> 2, p = c & 3;
        int gc = p ^ (row & 3);
        gld16(gbase + (size_t)row * DM + gc * 8, lbase + c * 8);
    }
}

// Fused Q/K/V projections, m97-style. 128x128 tile, BK=32, all bf16.
// grid (64, 18): sel = by/6 (0=Q 1=K 2=V), n0 = (by%6)*128.
__global__ __launch_bounds__(256) void gemm_qkv3(
    const u16* __restrict__ Xc, const u16* __restrict__ Wc, const u16* __restrict__ bc,
    u16* __restrict__ Yq, u16* __restrict__ Yk, u16* __restrict__ Yv) {
    __shared__ __align__(16) u16 As[2][128 * 32];
    __shared__ __align__(16) u16 Bs[2][128 * 32];

    const int by  = blockIdx.y;
    const int sel = by / 6;
    const int n0  = (by - sel * 6) * 128;
    const int m0  = blockIdx.x * 128;

    const u16* X  = Xc + (size_t)sel * NX;
    const u16* W  = Wc + (size_t)sel * WELEM;
    const u16* Bp = bc + sel * 768;
    u16* Y = sel == 0 ? Yq : (sel == 1 ? Yk : Yv);
    const float oscale = sel == 0 ? QSCALE : 1.0f;

    const int tid = threadIdx.x, lane = tid & 63, wave = tid >> 6;
    const int wr = (wave >> 1) * 64, wc2 = (wave & 1) * 64;
    const int l15 = lane & 15, quad = lane >> 4;
    const int ck = (quad ^ (l15 & 3)) * 8;   // swizzled k-chunk for frag reads

    f32x4 acc[4][4] = {};

    stage_g<512>(X + (size_t)m0 * DM, &As[0][0], tid);
    stage_g<512>(W + (size_t)n0 * DM, &Bs[0][0], tid);
    __syncthreads();

    for (int it = 0; it < 24; ++it) {
        const int cur = it & 1, nxt = cur ^ 1;
        if (it < 23) {
            stage_g<512>(X + (size_t)m0 * DM + (it + 1) * 32, &As[nxt][0], tid);
            stage_g<512>(W + (size_t)n0 * DM + (it + 1) * 32, &Bs[nxt][0], tid);
        }
        bf16x8 a[4], b[4];
#pragma unroll
        for (int i = 0; i < 4; ++i)
            a[i] = *(const bf16x8*)&As[cur][(wr + i * 16 + l15) * 32 + ck];
#pragma unroll
        for (int j = 0; j < 4; ++j)
            b[j] = *(const bf16x8*)&Bs[cur][(wc2 + j * 16 + l15) * 32 + ck];
#pragma unroll
        for (int i = 0; i < 4; ++i)
#pragma unroll
            for (int j = 0; j < 4; ++j)
                acc[i][j] = __builtin_amdgcn_mfma_f32_16x16x32_bf16(a[i], b[j], acc[i][j], 0, 0, 0);
        __syncthreads();   // frees cur for overwrite; drains nxt prefetch
    }

#pragma unroll
    for (int j = 0; j < 4; ++j) {
        int o = n0 + wc2 + j * 16 + l15;
        float bv = bf2f(Bp[o]);
        int h = o >> 6, d = o & 63;
#pragma unroll
        for (int i = 0; i < 4; ++i) {
            int row0 = m0 + wr + i * 16 + quad * 4;
            int bb = row0 >> 12, s0 = row0 & (SEQL - 1);
            if (sel < 2) {
#pragma unroll
                for (int r = 0; r < 4; ++r)
                    Y[((bb * HEADS + h) << 18) + ((s0 + r) << 6) + d] =
                        f2bf((acc[i][j][r] + bv) * oscale);
            } else {
                uint2 p = {cvt_pk(acc[i][j][0] + bv, acc[i][j][1] + bv),
                           cvt_pk(acc[i][j][2] + bv, acc[i][j][3] + bv)};
                *(uint2*)&Y[((bb * HEADS + h) << 18) + (d << 12) + s0] = p;
            }
        }
    }
}

// Output projection, m97-style. 64x128 tile, grid (128, 6) = 768 blocks = 3/CU.
__global__ __launch_bounds__(256) void gemm_out3(const u16* __restrict__ X,
                                                 const u16* __restrict__ W,
                                                 const u16* __restrict__ Bp,
                                                 void* __restrict__ Y,
                                                 const int* __restrict__ flag) {
    __shared__ __align__(16) u16 As[2][64 * 32];
    __shared__ __align__(16) u16 Bs[2][128 * 32];

    const int f32mode = *flag;
    const int m0 = blockIdx.x * 64, n0 = blockIdx.y * 128;
    const int tid = threadIdx.x, lane = tid & 63, wave = tid >> 6;
    const int wr = (wave >> 1) * 32, wc2 = (wave & 1) * 64;
    const int l15 = lane & 15, quad = lane >> 4;
    const int ck = (quad ^ (l15 & 3)) * 8;

    f32x4 acc[2][4] = {};

    stage_g<256>(X + (size_t)m0 * DM, &As[0][0], tid);
    stage_g<512>(W + (size_t)n0 * DM, &Bs[0][0], tid);
    __syncthreads();

    for (int it = 0; it < 24; ++it) {
        const int cur = it & 1, nxt = cur ^ 1;
        if (it < 23) {
            stage_g<256>(X + (size_t)m0 * DM + (it + 1) * 32, &As[nxt][0], tid);
            stage_g<512>(W + (size_t)n0 * DM + (it + 1) * 32, &Bs[nxt][0], tid);
        }
        bf16x8 a[2], b[4];
#pragma unroll
        for (int i = 0; i < 2; ++i)
            a[i] = *(const bf16x8*)&As[cur][(wr + i * 16 + l15) * 32 + ck];
#pragma unroll
        for (int j = 0; j < 4; ++j)
            b[j] = *(const bf16x8*)&Bs[cur][(wc2 + j * 16 + l15) * 32 + ck];
#pragma unroll
        for (int i = 0; i < 2; ++i)
#pragma unroll
            for (int j = 0; j < 4; ++j)
                acc[i][j] = __builtin_amdgcn_mfma_f32_16x16x32_bf16(a[i], b[j], acc[i][j], 0, 0, 0);
        __syncthreads();
    }

#pragma unroll
    for (int j = 0; j < 4; ++j) {
        int o = n0 + wc2 + j * 16 + l15;
        float bv = bf2f(Bp[o]);
#pragma unroll
        for (int i = 0; i < 2; ++i)
#pragma unroll
            for (int r = 0; r < 4; ++r) {
                int row = m0 + wr + i * 16 + quad * 4 + r;
                float val = acc[i][j][r] + bv;
                if (f32mode) ((float*)Y)[(size_t)row * DM + o] = val;
                else         ((u16*)Y)[(size_t)row * DM + o] = f2bf(val);
            }
    }
}

// ---- fallback GEMMs (R8 path, used only if workspace too small for Xc) ----
__device__ __forceinline__ void stage8_bf16(u16* dst, const u16* src) {
    *(uint4*)dst = *(const uint4*)src;
}
__device__ __forceinline__ void stage16_bf16(u16* dst, const u16* src) {
    *(uint4*)dst = *(const uint4*)src;
    *(uint4*)(dst + 8) = *(const uint4*)(src + 8);
}
__device__ __forceinline__ void stage16_f32pk(u16* dst, const float* src) {
    float4 f0 = ((const float4*)src)[0];
    float4 f1 = ((const float4*)src)[1];
    float4 f2 = ((const float4*)src)[2];
    float4 f3 = ((const float4*)src)[3];
    uint4 lo = {cvt_pk(f0.x, f0.y), cvt_pk(f0.z, f0.w), cvt_pk(f1.x, f1.y), cvt_pk(f1.z, f1.w)};
    uint4 hi = {cvt_pk(f2.x, f2.y), cvt_pk(f2.z, f2.w), cvt_pk(f3.x, f3.y), cvt_pk(f3.z, f3.w)};
    *(uint4*)dst = lo;
    *(uint4*)(dst + 8) = hi;
}

__global__ __launch_bounds__(256) void gemm_qkv_fb(
    const void* __restrict__ Xq, const void* __restrict__ Xk, const void* __restrict__ Xv,
    const u16* __restrict__ Wc, const u16* __restrict__ bc,
    u16* __restrict__ Yq, u16* __restrict__ Yk, u16* __restrict__ Yv,
    const int* __restrict__ flag) {
    __shared__ __align__(16) u16 As[128][40];
    __shared__ __align__(16) u16 Bs[64][40];
    const int f32mode = *flag;
    const int by = blockIdx.y;
    const int sel = by / 12;
    const int n0 = (by - sel * 12) * 64;
    const int m0 = blockIdx.x * 128;
    const void* Xp = sel == 0 ? Xq : (sel == 1 ? Xk : Xv);
    const u16* Wp = Wc + sel * WELEM;
    const u16* Bp = bc + sel * 768;
    u16* Y = sel == 0 ? Yq : (sel == 1 ? Yk : Yv);
    const float oscale = sel == 0 ? QSCALE : 1.0f;
    const int tid = threadIdx.x, lane = tid & 63, wave = tid >> 6;
    const int wr = (wave >> 1) * 64, wc = (wave & 1) * 32;
    const int l15 = lane & 15, quad = lane >> 4;
    const int srA = tid >> 1, scA = (tid & 1) * 16;
    const int srB = tid >> 2, scB = (tid & 3) * 8;
    f32x4 acc[4][2] = {};
    const size_t xoff = (size_t)(m0 + srA) * DM + scA;
    const size_t woff = (size_t)(n0 + srB) * DM + scB;
    for (int kb = 0; kb < DM; kb += 32) {
        if (f32mode) stage16_f32pk(&As[srA][scA], (const float*)Xp + xoff + kb);
        else         stage16_bf16(&As[srA][scA], (const u16*)Xp + xoff + kb);
        stage8_bf16(&Bs[srB][scB], Wp + woff + kb);
        __syncthreads();
        bf16x8 a[4], b[2];
#pragma unroll
        for (int i = 0; i < 4; ++i) a[i] = *(const bf16x8*)&As[wr + i * 16 + l15][quad * 8];
#pragma unroll
        for (int j = 0; j < 2; ++j) b[j] = *(const bf16x8*)&Bs[wc + j * 16 + l15][quad * 8];
#pragma unroll
        for (int i = 0; i < 4; ++i)
#pragma unroll
            for (int j = 0; j < 2; ++j)
                acc[i][j] = __builtin_amdgcn_mfma_f32_16x16x32_bf16(a[i], b[j], acc[i][j], 0, 0, 0);
        __syncthreads();
    }
#pragma unroll
    for (int j = 0; j < 2; ++j) {
        int o = n0 + wc + j * 16 + l15;
        float bv = bf2f(Bp[o]);
#pragma unroll
        for (int i = 0; i < 4; ++i)
#pragma unroll
            for (int r = 0; r < 4; ++r) {
                int row = m0 + wr + i * 16 + quad * 4 + r;
                float val = (acc[i][j][r] + bv) * oscale;
                int bb = row >> 12, s = row & (SEQL - 1);
                int h = o >> 6, d = o & 63;
                if (sel < 2) Y[((bb * HEADS + h) << 18) + (s << 6) + d] = f2bf(val);
                else         Y[((bb * HEADS + h) << 18) + (d << 12) + s] = f2bf(val);
            }
    }
}

__global__ __launch_bounds__(256) void gemm_out_fb(const u16* __restrict__ X,
                                                   const u16* __restrict__ Wp,
                                                   const u16* __restrict__ Bp,
                                                   void* __restrict__ Y,
                                                   const int* __restrict__ flag) {
    __shared__ __align__(16) u16 As[128][40];
    __shared__ __align__(16) u16 Bs[64][40];
    const int f32mode = *flag;
    const int m0 = blockIdx.x * 128, n0 = blockIdx.y * 64;
    const int tid = threadIdx.x, lane = tid & 63, wave = tid >> 6;
    const int wr = (wave >> 1) * 64, wc = (wave & 1) * 32;
    const int l15 = lane & 15, quad = lane >> 4;
    const int srA = tid >> 1, scA = (tid & 1) * 16;
    const int srB = tid >> 2, scB = (tid & 3) * 8;
    f32x4 acc[4][2] = {};
    const size_t xoff = (size_t)(m0 + srA) * DM + scA;
    const size_t woff = (size_t)(n0 + srB) * DM + scB;
    for (int kb = 0; kb < DM; kb += 32) {
        stage16_bf16(&As[srA][scA], X + xoff + kb);
        stage8_bf16(&Bs[srB][scB], Wp + woff + kb);
        __syncthreads();
        bf16x8 a[4], b[2];
#pragma unroll
        for (int i = 0; i < 4; ++i) a[i] = *(const bf16x8*)&As[wr + i * 16 + l15][quad * 8];
#pragma unroll
        for (int j = 0; j < 2; ++j) b[j] = *(const bf16x8*)&Bs[wc + j * 16 + l15][quad * 8];
#pragma unroll
        for (int i = 0; i < 4; ++i)
#pragma unroll
            for (int j = 0; j < 2; ++j)
                acc[i][j] = __builtin_amdgcn_mfma_f32_16x16x32_bf16(a[i], b[j], acc[i][j], 0, 0, 0);
        __syncthreads();
    }
#pragma unroll
    for (int j = 0; j < 2; ++j) {
        int o = n0 + wc + j * 16 + l15;
        float bv = bf2f(Bp[o]);
#pragma unroll
        for (int i = 0; i < 4; ++i)
#pragma unroll
            for (int r = 0; r < 4; ++r) {
                int row = m0 + wr + i * 16 + quad * 4 + r;
                float val = acc[i][j][r] + bv;
                if (f32mode) ((float*)Y)[(size_t)row * DM + o] = val;
                else         ((u16*)Y)[(size_t)row * DM + o] = f2bf(val);
            }
    }
}

// ---- flash v4 (unchanged from R7/R8) ----
__device__ __forceinline__ void stage_tile(const u16* gbase, int rstride,
                                           u16* lbase, int tid) {
#pragma unroll
    for (int it = 0; it < 2; ++it) {
        int c = it * 256 + tid;
        int row = c >> 3, p = c & 7;
        int gc = p ^ (row & 7);
        gld16(gbase + (size_t)row * rstride + gc * 8, lbase + c * 8);
    }
}

__global__ __launch_bounds__(256, 3) void flash_attn(const u16* __restrict__ Q,
                                                     const u16* __restrict__ K,
                                                     const u16* __restrict__ Vt,
                                                     const int* __restrict__ mask,
                                                     u16* __restrict__ ctx) {
    __shared__ __align__(16) u16 Ks[2][64 * 64];
    __shared__ __align__(16) u16 Vs[2][64 * 64];
    __shared__ __align__(16) float Ms[2][64];
    __shared__ __align__(16) u16 Ps[4][32 * 72];

    const int tid  = threadIdx.x;
    const int lane = tid & 63;
    const int wave = tid >> 6;
    const int l15  = lane & 15;
    const int quad = lane >> 4;

    const int bh = blockIdx.y;
    const int b  = bh / HEADS;
    const int h  = bh - b * HEADS;
    const int qb = blockIdx.x * 128 + wave * 32;

    const u16* Qh = Q  + ((size_t)bh << 18);
    const u16* Kh = K  + ((size_t)bh << 18);
    const u16* Vh = Vt + ((size_t)bh << 18);
    const int* maskb = mask + b * SEQL;

    bf16x8 aq[2][2];
#pragma unroll
    for (int s = 0; s < 2; ++s)
#pragma unroll
        for (int c = 0; c < 2; ++c)
            aq[s][c] = *(const bf16x8*)&Qh[(size_t)(qb + s * 16 + l15) * DK + c * 32 + quad * 8];

    const int r7   = l15 & 7;
    const int ck0  = (quad ^ r7) * 8;
    const int ck1  = ((quad + 4) ^ r7) * 8;
    const int lrow = l15 * 64;

    float m_s[2] = {-3.0e38f, -3.0e38f}, l_s[2] = {0.f, 0.f};
    f32x4 o_acc[2][4] = {};

    int mreg = 0;
    if (tid < 64) mreg = maskb[tid];
    stage_tile(Kh, DK, &Ks[0][0], tid);
    stage_tile(Vh, SEQL, &Vs[0][0], tid);
    if (tid < 64) {
        Ms[0][tid] = (mreg == 0) ? -1.0e9f : 0.0f;
        mreg = maskb[64 + tid];
    }
    __syncthreads();

    for (int t = 0; t < 64; ++t) {
        const int cur = t & 1, nxt = cur ^ 1;
        if (t < 63) {
            const int kt = (t + 1) * 64;
            stage_tile(Kh + (size_t)kt * DK, DK, &Ks[nxt][0], tid);
            stage_tile(Vh + kt, SEQL, &Vs[nxt][0], tid);
            if (tid < 64) {
                Ms[nxt][tid] = (mreg == 0) ? -1.0e9f : 0.0f;
                if (t < 62) mreg = maskb[(t + 2) * 64 + tid];
            }
        }

        const u16* kb = &Ks[cur][0];
        const u16* vb = &Vs[cur][0];

        f32x4 s4[2][4];
#pragma unroll
        for (int nt = 0; nt < 4; ++nt) {
            bf16x8 ak0 = *(const bf16x8*)&kb[lrow + nt * 1024 + ck0];
            bf16x8 ak1 = *(const bf16x8*)&kb[lrow + nt * 1024 + ck1];
            f32x4 bias = *(const f32x4*)&Ms[cur][nt * 16 + quad * 4];
#pragma unroll
            for (int s = 0; s < 2; ++s) {
                f32x4 z = {};
                z = __builtin_amdgcn_mfma_f32_16x16x32_bf16(ak0, aq[s][0], z, 0, 0, 0);
                z = __builtin_amdgcn_mfma_f32_16x16x32_bf16(ak1, aq[s][1], z, 0, 0, 0);
#pragma unroll
                for (int r = 0; r < 4; ++r) s4[s][nt][r] = z[r] + bias[r];
            }
        }

        float newm[2], rs[2];
#pragma unroll
        for (int s = 0; s < 2; ++s) {
            float mx = -3.0e38f;
#pragma unroll
            for (int nt = 0; nt < 4; ++nt)
#pragma unroll
                for (int r = 0; r < 4; ++r) mx = fmaxf(mx, s4[s][nt][r]);
            mx = fmaxf(mx, __shfl_xor(mx, 16, 64));
            mx = fmaxf(mx, __shfl_xor(mx, 32, 64));
            newm[s] = fmaxf(m_s[s], mx);

            float r2 = 0.f;
#pragma unroll
            for (int nt = 0; nt < 4; ++nt)
#pragma unroll
                for (int r = 0; r < 4; ++r) {
                    float p = EXP2F(s4[s][nt][r] - newm[s]);
                    s4[s][nt][r] = p;
                    r2 += p;
                }
            r2 += __shfl_xor(r2, 16, 64);
            r2 += __shfl_xor(r2, 32, 64);
            rs[s] = r2;
        }

        if (!__all(newm[0] == m_s[0] && newm[1] == m_s[1])) {
#pragma unroll
            for (int s = 0; s < 2; ++s) {
                float alpha = EXP2F(m_s[s] - newm[s]);
                l_s[s] *= alpha;
#pragma unroll
                for (int dv = 0; dv < 4; ++dv)
#pragma unroll
                    for (int r = 0; r < 4; ++r) o_acc[s][dv][r] *= alpha;
                m_s[s] = newm[s];
            }
        }
        l_s[0] += rs[0];
        l_s[1] += rs[1];

#pragma unroll
        for (int s = 0; s < 2; ++s)
#pragma unroll
            for (int nt = 0; nt < 4; ++nt) {
                uint2 cv = {cvt_pk(s4[s][nt][0], s4[s][nt][1]),
                            cvt_pk(s4[s][nt][2], s4[s][nt][3])};
                *(uint2*)&Ps[wave][(s * 16 + l15) * 72 + nt * 16 + quad * 4] = cv;
            }
        asm volatile("" ::: "memory");

        bf16x8 bp[2][2];
#pragma unroll
        for (int s = 0; s < 2; ++s)
#pragma unroll
            for (int c = 0; c < 2; ++c)
                bp[s][c] = *(const bf16x8*)&Ps[wave][(s * 16 + l15) * 72 + c * 32 + quad * 8];

#pragma unroll
        for (int dv = 0; dv < 4; ++dv) {
            bf16x8 av0 = *(const bf16x8*)&vb[lrow + dv * 1024 + ck0];
            bf16x8 av1 = *(const bf16x8*)&vb[lrow + dv * 1024 + ck1];
#pragma unroll
            for (int s = 0; s < 2; ++s) {
                o_acc[s][dv] = __builtin_amdgcn_mfma_f32_16x16x32_bf16(av0, bp[s][0], o_acc[s][dv], 0, 0, 0);
                o_acc[s][dv] = __builtin_amdgcn_mfma_f32_16x16x32_bf16(av1, bp[s][1], o_acc[s][dv], 0, 0, 0);
            }
        }
        __syncthreads();
    }

#pragma unroll
    for (int s = 0; s < 2; ++s) {
        float inv = 1.0f / l_s[s];
#pragma unroll
        for (int dv = 0; dv < 4; ++dv) {
            uint2 cv = {cvt_pk(o_acc[s][dv][0] * inv, o_acc[s][dv][1] * inv),
                        cvt_pk(o_acc[s][dv][2] * inv, o_acc[s][dv][3] * inv)};
            *(uint2*)&Ps[wave][(s * 16 + l15) * 72 + dv * 16 + quad * 4] = cv;
        }
    }
    asm volatile("" ::: "memory");
    {
        int rowq = lane >> 2, dchunk = lane & 3;
#pragma unroll
        for (int s = 0; s < 2; ++s) {
            uint4 w0 = *(const uint4*)&Ps[wave][(s * 16 + rowq) * 72 + dchunk * 16];
            uint4 w1 = *(const uint4*)&Ps[wave][(s * 16 + rowq) * 72 + dchunk * 16 + 8];
            size_t orow = (size_t)(b * SEQL + qb + s * 16 + rowq) * DM + h * DK + dchunk * 16;
            *(uint4*)&ctx[orow] = w0;
            *(uint4*)&ctx[orow + 8] = w1;
        }
    }
}

extern "C" void kernel_launch(void* const* d_in, const int* in_sizes, int n_in,
                              void* d_out, int out_size, void* d_ws, size_t ws_size,
                              hipStream_t stream) {
    const void* q   = d_in[0];
    const void* k   = d_in[1];
    const void* v   = d_in[2];
    const void* Wq  = d_in[3];
    const void* bq  = d_in[4];
    const void* Wk  = d_in[5];
    const void* bk  = d_in[6];
    const void* Wv  = d_in[7];
    const void* bv  = d_in[8];
    const void* Wo  = d_in[9];
    const void* bo  = d_in[10];
    const int* mask = (const int*)d_in[11];

    const size_t NSH = (size_t)NX;   // per-tensor head-split elems
    u16* ws = (u16*)d_ws;

    // Full layout: [Qh][Kh][Vth][Xc0=ctx][Xc1][Xc2][Wc][bc][flag]
    const size_t need_full = (6 * NSH + WTOT + BTOT) * sizeof(u16) + 64;
    const size_t need_fb   = (4 * NSH + WTOT + BTOT) * sizeof(u16) + 64;

    if (ws_size >= need_full) {
        u16* Qh  = ws;
        u16* Kh  = ws + NSH;
        u16* Vth = ws + 2 * NSH;
        u16* Xc  = ws + 3 * NSH;       // 3*NSH; Xc0 region doubles as ctx
        u16* ctx = Xc;                 // alias: Xc consumed before flash writes ctx
        u16* Wc  = ws + 6 * NSH;
        u16* bc  = Wc + WTOT;
        int* dflag = (int*)(bc + BTOT);

        detect_dtype<<<1, 256, 0, stream>>>((const u16*)q, dflag);
        convert_x<<<(3 * NX / 8 + 255) / 256, 256, 0, stream>>>(q, k, v, Xc, dflag);
        convert_wb<<<((WTOT + BTOT) / 4 + 255) / 256, 256, 0, stream>>>(
            Wq, Wk, Wv, Wo, bq, bk, bv, bo, Wc, bc, dflag);

        gemm_qkv3<<<dim3(MROWS / 128, 18), 256, 0, stream>>>(Xc, Wc, bc, Qh, Kh, Vth);
        flash_attn<<<dim3(SEQL / 128, BSZ * HEADS), 256, 0, stream>>>(Qh, Kh, Vth, mask, ctx);
        gemm_out3<<<dim3(MROWS / 64, 6), 256, 0, stream>>>(
            ctx, Wc + 3 * (size_t)WELEM, bc + 3 * 768, d_out, dflag);
    } else if (ws_size >= need_fb) {
        u16* Qh  = ws;
        u16* Kh  = ws + NSH;
        u16* Vth = ws + 2 * NSH;
        u16* ctx = ws + 3 * NSH;
        u16* Wc  = ws + 4 * NSH;
        u16* bc  = Wc + WTOT;
        int* dflag = (int*)(bc + BTOT);

        detect_dtype<<<1, 256, 0, stream>>>((const u16*)q, dflag);
        convert_wb<<<((WTOT + BTOT) / 4 + 255) / 256, 256, 0, stream>>>(
            Wq, Wk, Wv, Wo, bq, bk, bv, bo, Wc, bc, dflag);
        gemm_qkv_fb<<<dim3(MROWS / 128, 36), 256, 0, stream>>>(
            q, k, v, Wc, bc, Qh, Kh, Vth, dflag);
        flash_attn<<<dim3(SEQL / 128, BSZ * HEADS), 256, 0, stream>>>(Qh, Kh, Vth, mask, ctx);
        gemm_out_fb<<<dim3(MROWS / 128, 12), 256, 0, stream>>>(
            ctx, Wc + 3 * (size_t)WELEM, bc + 3 * 768, d_out, dflag);
    }
}